// Round 12
// baseline (32.297 us; speedup 1.0000x reference)
//
#include <hip/hip_runtime.h>

// PatchStd: out = sqrt( boxconv7(x^2) - boxconv7(x)^2 ), uniform 7x7 weight w.
// x: [16, 1, 1024, 1024] fp32, zero padding 3 on each side.
//
// Structure = R11 (wave-private LDS row-ring, RING=4, global_load_lds DMA
// 3 rows ahead, exact counted s_waitcnt vmcnt, SH=16, 1024 co-resident
// blocks) with ONE change: output rows are buffered in REGISTERS (16 x
// float4) and stored in a burst AFTER the last consume. vmcnt retires
// in-order, so an in-loop store makes every later load-wait transitively
// wait on store-to-L2 acks; with stores deferred the loop's vm queue holds
// loads only (clean WAITV(6) steady state). +64 VGPR -> ~124, still 4
// waves/SIMD — free (LDS caps residency at 4 blocks/CU regardless).
// SEGF=320 is the full 64-lane DMA footprint (R9 lesson). No barriers.

#define IMG_W 1024
#define IMG_H 1024
#define SH    16            // output rows per block strip
#define TPB   256
#define NR    (SH + 6)      // 22 input rows per strip
#define RING  4
#define SEGF  320           // floats per LDS slot (272 used; 320 = DMA footprint)

typedef float v4f __attribute__((ext_vector_type(4)));

#define WAITV(N) asm volatile("s_waitcnt vmcnt(" #N ")" ::: "memory")

__global__ __launch_bounds__(TPB) void patchstd_kernel(
    const float* __restrict__ img, const float* __restrict__ wptr,
    float* __restrict__ out)
{
    __shared__ float lds[4 * RING * SEGF];          // 20 KB

    const int tx   = threadIdx.x;
    const int w_   = tx >> 6;                       // wave id 0..3 (uniform)
    const int lane = tx & 63;
    const int c0   = tx << 2;                       // first of 4 output cols
    const int y0   = blockIdx.y * SH;
    const float* base  = img + (size_t)blockIdx.z * (IMG_W * IMG_H);
    float*       obase = out + (size_t)blockIdx.z * (IMG_W * IMG_H);
    const float w = wptr[0];

    // Wave w_ covers output cols [256w, 256w+256); segment = cols Sw..Sw+271
    // (Sw = 256w-8); thread's 12-float window (c0-4..c0+7) is at segment
    // float index 4*lane+4. Per-lane global cols clamped in-row (clamped
    // lanes land in padding or are zero-patched at consume).
    const int Sw   = 256 * w_ - 8;
    const int colA = min(max(Sw + 4 * lane, 0), IMG_W - 4);   // dwordx4 quad
    const int colB = min(max(Sw + 256 + lane, 0), IMG_W - 1); // dword tail
    const float* gA = base + colA;
    const float* gB = base + colB;
    float* const seg0 = &lds[w_ * (RING * SEGF)];

    // Issue row j's segment DMA into ring slot j&3 (wave-uniform LDS base).
    auto issue = [&](int j) {
        const int rc = min(max(y0 - 3 + j, 0), IMG_H - 1);    // clamped row
        const size_t ro = (size_t)rc * IMG_W;
        float* sl = seg0 + (j & (RING - 1)) * SEGF;
        __builtin_amdgcn_global_load_lds(
            (const __attribute__((address_space(1))) void*)(gA + ro),
            (__attribute__((address_space(3))) void*)sl, 16, 0, 0);
        __builtin_amdgcn_global_load_lds(
            (const __attribute__((address_space(1))) void*)(gB + ro),
            (__attribute__((address_space(3))) void*)(sl + 256), 4, 0, 0);
    };

    // Horizontal 7-sums for 4 output cols from 12 raw values
    // (window for col c0+k = v[k+1..k+7]).
    auto hsum = [&](const float* v, float* h, float* q) {
        float s = v[1]+v[2]+v[3]+v[4]+v[5]+v[6]+v[7];
        h[0] = s;
        s = s - v[1] + v[8];  h[1] = s;
        s = s - v[2] + v[9];  h[2] = s;
        h[3] = s - v[3] + v[10];
        float sq[11];
        #pragma unroll
        for (int i = 1; i <= 10; ++i) sq[i] = v[i] * v[i];
        float t = sq[1]+sq[2]+sq[3]+sq[4]+sq[5]+sq[6]+sq[7];
        q[0] = t;
        t = t - sq[1] + sq[8];  q[1] = t;
        t = t - sq[2] + sq[9];  q[2] = t;
        q[3] = t - sq[3] + sq[10];
    };

    float rh[7][4], rq[7][4];                       // h/q ring (7 rows)
    float vh[4] = {0.f,0.f,0.f,0.f};                // vertical running sums
    float vq[4] = {0.f,0.f,0.f,0.f};
    v4f  obuf[SH];                                  // deferred output rows

    issue(0); issue(1); issue(2);                   // 3-deep pipeline fill

    // Full unroll: ring slots, vmcnt immediates, guards all compile-time.
    // Loads ONLY in the vm queue (stores deferred): outstanding after
    // issue at iter j = 2*(min(j+3,21)-j): j<=18 -> 6, 19 -> 4, 20 -> 2,
    // 21 -> 0 (final consume; nothing left to overlap).
    #pragma unroll
    for (int j = 0; j < NR; ++j) {
        if (j + 3 < NR) issue(j + 3);

        if      (j <= 18) WAITV(6);
        else if (j == 19) WAITV(4);
        else if (j == 20) WAITV(2);
        else              WAITV(0);

        // Consume row j from LDS: 3x ds_read_b128.
        const float* seg = seg0 + (j & (RING - 1)) * SEGF;
        const v4f* p = (const v4f*)(seg + 4 * lane + 4);
        v4f A = p[0], B = p[1], C = p[2];
        float v[12] = {A.x,A.y,A.z,A.w, B.x,B.y,B.z,B.w, C.x,C.y,C.z,C.w};
        if (tx == 0)   { v[0]=0.f; v[1]=0.f; v[2]=0.f;  v[3]=0.f;  }
        if (tx == 255) { v[8]=0.f; v[9]=0.f; v[10]=0.f; v[11]=0.f; }

        float h[4], q[4];
        const int R = y0 - 3 + j;
        if (R < 0 || R >= IMG_H) {                  // block-uniform branch
            #pragma unroll
            for (int k = 0; k < 4; ++k) { h[k] = 0.f; q[k] = 0.f; }
        } else {
            hsum(v, h, q);
        }

        if (j < 6) {                                // warm the vertical window
            #pragma unroll
            for (int k = 0; k < 4; ++k) {
                rh[j][k] = h[k]; rq[j][k] = q[k];
                vh[k] += h[k];   vq[k] += q[k];
            }
            if (j == 5) {
                #pragma unroll
                for (int k = 0; k < 4; ++k) { rh[6][k] = 0.f; rq[6][k] = 0.f; }
            }
        } else {                                    // steady state: buffer a row
            const int s = j % 7;                    // departing row's slot
            float o[4];
            #pragma unroll
            for (int k = 0; k < 4; ++k) {
                vh[k] += h[k] - rh[s][k];
                vq[k] += q[k] - rq[s][k];
                rh[s][k] = h[k]; rq[s][k] = q[k];
                float mean = w * vh[k];
                float var  = fmaf(w, vq[k], -(mean * mean));
                o[k] = __builtin_amdgcn_sqrtf(fmaxf(var, 0.f));
            }
            v4f ov; ov.x = o[0]; ov.y = o[1]; ov.z = o[2]; ov.w = o[3];
            obuf[j - 6] = ov;                       // static index (unrolled)
        }
    }

    // Store burst: 16 coalesced dwordx4 rows, after all loads retired.
    #pragma unroll
    for (int rr = 0; rr < SH; ++rr) {
        *reinterpret_cast<v4f*>(obase + (size_t)(y0 + rr) * IMG_W + c0) =
            obuf[rr];
    }
}

extern "C" void kernel_launch(void* const* d_in, const int* in_sizes, int n_in,
                              void* d_out, int out_size, void* d_ws, size_t ws_size,
                              hipStream_t stream) {
    const float* img = (const float*)d_in[0];
    const float* wt  = (const float*)d_in[1];
    float* out = (float*)d_out;
    const int batch = in_sizes[0] / (IMG_W * IMG_H);   // 16
    dim3 grid(1, IMG_H / SH, batch);                   // 1024 blocks, co-resident
    patchstd_kernel<<<grid, dim3(TPB, 1, 1), 0, stream>>>(img, wt, out);
}

// Round 13
// 29.459 us; speedup vs baseline: 1.0963x; 1.0963x over previous
//
#include <hip/hip_runtime.h>

// PatchStd: out = sqrt( boxconv7(x^2) - boxconv7(x)^2 ), uniform 7x7 weight w.
// x: [16, 1, 1024, 1024] fp32, zero padding 3 on each side.
//
// Base = R11 (best, 29.0us): wave-private LDS row-ring, RING=4, DMA 3 rows
// ahead via global_load_lds, counted s_waitcnt vmcnt, SH=16, 1024
// co-resident blocks, stores in-loop (R12 proved deferring regresses).
// NEW: consume is software-pipelined by ONE row — row j's 12 raw floats
// live in regs (rv[2][12], parity static under full unroll); per iter:
// issue DMA(j+3); hsum+store row j from regs; WAITV(row j+1); ds_read row
// j+1 into other buffer. vm-wait overlaps the VALU work; ds_read->use
// distance = 1 iteration (lgkm wait off the critical path).
// Wait table derived for op order [L(j+3); S(j-6); WAIT; ds_read]:
//   pre:4 | j<=5:4 | j6:5 | j7:6 | j8-18:7 | j19:5 | j20:3 | j21:none.
// SEGF=320 = full 64-lane DMA footprint (R9 lesson). No barriers.

#define IMG_W 1024
#define IMG_H 1024
#define SH    16            // output rows per block strip
#define TPB   256
#define NR    (SH + 6)      // 22 input rows per strip
#define RING  4
#define SEGF  320           // floats per LDS slot (272 used; 320 = DMA footprint)

typedef float v4f __attribute__((ext_vector_type(4)));

#define WAITV(N) asm volatile("s_waitcnt vmcnt(" #N ")" ::: "memory")

__global__ __launch_bounds__(TPB) void patchstd_kernel(
    const float* __restrict__ img, const float* __restrict__ wptr,
    float* __restrict__ out)
{
    __shared__ float lds[4 * RING * SEGF];          // 20 KB

    const int tx   = threadIdx.x;
    const int w_   = tx >> 6;                       // wave id 0..3 (uniform)
    const int lane = tx & 63;
    const int c0   = tx << 2;                       // first of 4 output cols
    const int y0   = blockIdx.y * SH;
    const float* base  = img + (size_t)blockIdx.z * (IMG_W * IMG_H);
    float*       obase = out + (size_t)blockIdx.z * (IMG_W * IMG_H);
    const float w = wptr[0];

    // Wave w_ covers output cols [256w, 256w+256); segment = cols Sw..Sw+271
    // (Sw = 256w-8); thread's 12-float window (c0-4..c0+7) is at segment
    // float index 4*lane+4. Per-lane global cols clamped in-row.
    const int Sw   = 256 * w_ - 8;
    const int colA = min(max(Sw + 4 * lane, 0), IMG_W - 4);   // dwordx4 quad
    const int colB = min(max(Sw + 256 + lane, 0), IMG_W - 1); // dword tail
    const float* gA = base + colA;
    const float* gB = base + colB;
    float* const seg0 = &lds[w_ * (RING * SEGF)];

    // Issue row j's segment DMA into ring slot j&3 (wave-uniform LDS base).
    auto issue = [&](int j) {
        const int rc = min(max(y0 - 3 + j, 0), IMG_H - 1);    // clamped row
        const size_t ro = (size_t)rc * IMG_W;
        float* sl = seg0 + (j & (RING - 1)) * SEGF;
        __builtin_amdgcn_global_load_lds(
            (const __attribute__((address_space(1))) void*)(gA + ro),
            (__attribute__((address_space(3))) void*)sl, 16, 0, 0);
        __builtin_amdgcn_global_load_lds(
            (const __attribute__((address_space(1))) void*)(gB + ro),
            (__attribute__((address_space(3))) void*)(sl + 256), 4, 0, 0);
    };

    // ds_read row j's 12-float window into v[12] (+ edge zero-patch).
    auto ldrow = [&](int j, float* v) {
        const float* seg = seg0 + (j & (RING - 1)) * SEGF;
        const v4f* p = (const v4f*)(seg + 4 * lane + 4);
        v4f A = p[0], B = p[1], C = p[2];
        v[0]=A.x; v[1]=A.y; v[2]=A.z;  v[3]=A.w;
        v[4]=B.x; v[5]=B.y; v[6]=B.z;  v[7]=B.w;
        v[8]=C.x; v[9]=C.y; v[10]=C.z; v[11]=C.w;
        if (tx == 0)   { v[0]=0.f; v[1]=0.f; v[2]=0.f;  v[3]=0.f;  }
        if (tx == 255) { v[8]=0.f; v[9]=0.f; v[10]=0.f; v[11]=0.f; }
    };

    // Horizontal 7-sums for 4 output cols (window for col c0+k = v[k+1..k+7]).
    auto hsum = [&](const float* v, float* h, float* q) {
        float s = v[1]+v[2]+v[3]+v[4]+v[5]+v[6]+v[7];
        h[0] = s;
        s = s - v[1] + v[8];  h[1] = s;
        s = s - v[2] + v[9];  h[2] = s;
        h[3] = s - v[3] + v[10];
        float sq[11];
        #pragma unroll
        for (int i = 1; i <= 10; ++i) sq[i] = v[i] * v[i];
        float t = sq[1]+sq[2]+sq[3]+sq[4]+sq[5]+sq[6]+sq[7];
        q[0] = t;
        t = t - sq[1] + sq[8];  q[1] = t;
        t = t - sq[2] + sq[9];  q[2] = t;
        q[3] = t - sq[3] + sq[10];
    };

    float rh[7][4], rq[7][4];                       // h/q ring (7 rows)
    float vh[4] = {0.f,0.f,0.f,0.f};                // vertical running sums
    float vq[4] = {0.f,0.f,0.f,0.f};
    float rv[2][12];                                // raw-row reg pipeline

    issue(0); issue(1); issue(2);                   // 3-deep pipeline fill
    WAITV(4);                                       // row 0 arrived
    ldrow(0, rv[0]);

    // Full unroll: ring slots, parity, vmcnt immediates, guards static.
    // Iter j: consume row j (from rv[j&1]); emit output row j-6 for j>=6;
    // then wait for row j+1 and ds_read it into rv[(j+1)&1].
    #pragma unroll
    for (int j = 0; j < NR; ++j) {
        if (j + 3 < NR) issue(j + 3);

        float h[4], q[4];
        const int R = y0 - 3 + j;
        if (R < 0 || R >= IMG_H) {                  // block-uniform branch
            #pragma unroll
            for (int k = 0; k < 4; ++k) { h[k] = 0.f; q[k] = 0.f; }
        } else {
            hsum(rv[j & 1], h, q);
        }

        if (j < 6) {                                // warm the vertical window
            #pragma unroll
            for (int k = 0; k < 4; ++k) {
                rh[j][k] = h[k]; rq[j][k] = q[k];
                vh[k] += h[k];   vq[k] += q[k];
            }
            if (j == 5) {
                #pragma unroll
                for (int k = 0; k < 4; ++k) { rh[6][k] = 0.f; rq[6][k] = 0.f; }
            }
        } else {                                    // steady state: emit a row
            const int s = j % 7;                    // departing row's slot
            float o[4];
            #pragma unroll
            for (int k = 0; k < 4; ++k) {
                vh[k] += h[k] - rh[s][k];
                vq[k] += q[k] - rq[s][k];
                rh[s][k] = h[k]; rq[s][k] = q[k];
                float mean = w * vh[k];
                float var  = fmaf(w, vq[k], -(mean * mean));
                o[k] = __builtin_amdgcn_sqrtf(fmaxf(var, 0.f));
            }
            *reinterpret_cast<float4*>(obase + (size_t)(y0 + j - 6) * IMG_W + c0) =
                make_float4(o[0], o[1], o[2], o[3]);
        }

        // Pipeline: ensure row j+1 arrived, read it into the other buffer.
        if (j + 1 < NR) {
            if      (j <= 5)  WAITV(4);
            else if (j == 6)  WAITV(5);
            else if (j == 7)  WAITV(6);
            else if (j <= 18) WAITV(7);
            else if (j == 19) WAITV(5);
            else              WAITV(3);             // j == 20
            ldrow(j + 1, rv[(j + 1) & 1]);
        }
    }
}

extern "C" void kernel_launch(void* const* d_in, const int* in_sizes, int n_in,
                              void* d_out, int out_size, void* d_ws, size_t ws_size,
                              hipStream_t stream) {
    const float* img = (const float*)d_in[0];
    const float* wt  = (const float*)d_in[1];
    float* out = (float*)d_out;
    const int batch = in_sizes[0] / (IMG_W * IMG_H);   // 16
    dim3 grid(1, IMG_H / SH, batch);                   // 1024 blocks, co-resident
    patchstd_kernel<<<grid, dim3(TPB, 1, 1), 0, stream>>>(img, wt, out);
}